// Round 9
// baseline (373.567 us; speedup 1.0000x reference)
//
#include <hip/hip_runtime.h>

#define B_    128
#define NELEC 192
#define NAO   128
#define NMO   96
#define NCONF 32
#define L_    80

__global__ void zero_out_k(float* out) { if (threadIdx.x < B_) out[threadIdx.x] = 0.f; }

// G[b][s][m] = sum_n ao[b][2s][n] * mo_w[m][n]; blocks with st==0 also zero out[b]
__global__ __launch_bounds__(256) void gemm_g_k(const float* __restrict__ ao,
                                                const float* __restrict__ mo_w,
                                                float* __restrict__ G,
                                                float* __restrict__ out) {
    int b  = blockIdx.x;
    int st = blockIdx.y;
    int tid = threadIdx.x;
    if (st == 0 && tid == 0) out[b] = 0.f;
    int s_local = tid >> 4;
    int m0 = (tid & 15) * 6;
    int s = st * 16 + s_local;
    const float* arow = ao + ((size_t)b * NELEC + 2 * s) * NAO;
    const float* w0   = mo_w + (size_t)m0 * NAO;
    float acc[6] = {0.f, 0.f, 0.f, 0.f, 0.f, 0.f};
    for (int n = 0; n < NAO; n += 4) {
        float4 av = *(const float4*)(arow + n);
#pragma unroll
        for (int q = 0; q < 6; ++q) {
            float4 wv = *(const float4*)(w0 + (size_t)q * NAO + n);
            acc[q] += av.x * wv.x + av.y * wv.y + av.z * wv.z + av.w * wv.w;
        }
    }
    float* grow = G + ((size_t)b * NMO + s) * NMO + m0;
#pragma unroll
    for (int q = 0; q < 6; ++q) grow[q] = acc[q];
}

__device__ __forceinline__ float rdlane(float x, int src) {
    return __int_as_float(__builtin_amdgcn_readlane(__float_as_int(x), src));
}
__device__ __forceinline__ int rdlanei(int x, int src) {
    return __builtin_amdgcn_readlane(x, src);
}
#define DPPMAX(v, ctrl)                                                          \
    v = fmaxf(v, __int_as_float(__builtin_amdgcn_update_dpp(                     \
            __float_as_int(v), __float_as_int(v), (ctrl), 0xf, 0xf, false)))

// Round-6 body, shared by both A/B kernels (inlined; regalloc happens per
// kernel AFTER inlining, so the waves_per_eu attribute on the caller governs).
template <bool USE_G>
__device__ __forceinline__ void det_body(const float* __restrict__ ao,
                                         const float* __restrict__ mo_w,
                                         const float* __restrict__ G,
                                         const float* __restrict__ ci_w,
                                         const int* __restrict__ conf_idx,
                                         float* __restrict__ out) {
    __shared__ __align__(16) float Ms[40][84];
    __shared__ int sIdx[L_];
    __shared__ int tbl[64];

    int c = blockIdx.x;                // pointers pre-offset by caller
    int b = blockIdx.y;
    int lane = threadIdx.x;

    if (lane < 64) sIdx[lane] = conf_idx[c * L_ + lane] >> 1;
    if (lane < 16) sIdx[64 + lane] = conf_idx[c * L_ + 64 + lane] >> 1;
    __syncthreads();

    float a[81];
#pragma unroll
    for (int t = 0; t < 81; ++t) a[t] = 0.f;

    const float* Gb = G + (size_t)b * NMO * NMO;

#pragma unroll 1
    for (int pass = 0; pass < 2; ++pass) {
        int r0 = pass * 40;
        for (int e = lane; e < 40 * L_; e += 64) {
            int i = e / L_, j = e - i * L_;
            float v;
            if (USE_G) {
                v = Gb[(size_t)sIdx[r0 + i] * NMO + sIdx[j]];
            } else {
                const float* ar = ao + ((size_t)b * NELEC + 2 * sIdx[r0 + i]) * NAO;
                const float* wr = mo_w + (size_t)sIdx[j] * NAO;
                float acc = 0.f;
                for (int n = 0; n < NAO; n += 4) {
                    float4 av = *(const float4*)(ar + n);
                    float4 wv = *(const float4*)(wr + n);
                    acc += av.x * wv.x + av.y * wv.y + av.z * wv.z + av.w * wv.w;
                }
                v = acc;
            }
            Ms[i][j] = v;
        }
        __syncthreads();
        if (pass == 0) {
            if (lane < 40) {
#pragma unroll
                for (int q = 0; q < 20; ++q) {
                    float4 v4 = *(const float4*)&Ms[lane][4 * q];
                    a[4 * q] = v4.x; a[4 * q + 1] = v4.y; a[4 * q + 2] = v4.z; a[4 * q + 3] = v4.w;
                }
            }
        } else {
            if (lane >= 40) {
#pragma unroll
                for (int q = 0; q < 20; ++q) {
                    float4 v4 = *(const float4*)&Ms[lane - 40][4 * q];
                    a[4 * q] = v4.x; a[4 * q + 1] = v4.y; a[4 * q + 2] = v4.z; a[4 * q + 3] = v4.w;
                }
            }
        }
        __syncthreads();
    }

    double det = 1.0;
    int inv = 0;
    bool act = true;

    // ---------------- phase 1: k = 0..15 ----------------
#pragma unroll 1
    for (int k = 0; k < 16; ++k) {
        int rem = 79 - k;
        float cand = act ? fabsf(a[0]) : -1.f;
        float m = cand;
        DPPMAX(m, 0x111); DPPMAX(m, 0x112); DPPMAX(m, 0x114); DPPMAX(m, 0x118);
        DPPMAX(m, 0x142); DPPMAX(m, 0x143);
        float mx = rdlane(m, 63);
        unsigned long long sel = __ballot(act && cand == mx);
        int p = __ffsll(sel) - 1;

        inv += __popcll(__ballot(act && lane < p));

        float piv = rdlane(a[0], p);
        det *= (double)piv;
        if (lane == p) act = false;
        float la = (act && piv != 0.f) ? a[0] / piv : 0.f;

        if (lane < 16) {
            float* Brow = &Ms[24 + lane][0];
            float4 Qc = *(const float4*)&Brow[0];
            float lb = (piv != 0.f) ? Qc.x / piv : 0.f;
#pragma unroll
            for (int tb = 0; tb < 5; ++tb) {
                if (16 * tb < rem) {
#pragma unroll
                    for (int j = 0; j < 4; ++j) {
                        float4 Qn = *(const float4*)&Brow[16 * tb + 4 * j + 4];
                        float4 W;
                        W.x = fmaf(-lb, rdlane(a[16 * tb + 4 * j + 1], p), Qc.y);
                        W.y = fmaf(-lb, rdlane(a[16 * tb + 4 * j + 2], p), Qc.z);
                        W.z = fmaf(-lb, rdlane(a[16 * tb + 4 * j + 3], p), Qc.w);
                        W.w = fmaf(-lb, rdlane(a[16 * tb + 4 * j + 4], p), Qn.x);
                        *(float4*)&Brow[16 * tb + 4 * j] = W;
                        Qc = Qn;
                    }
                }
            }
        }

#pragma unroll
        for (int tb = 0; tb < 5; ++tb) {
            if (16 * tb < rem) {
#pragma unroll
                for (int i = 0; i < 16; ++i) {
                    float u = rdlane(a[16 * tb + i + 1], p);
                    a[16 * tb + i] = fmaf(-la, u, a[16 * tb + i + 1]);
                }
            }
        }
    }

    // ---------------- compaction ----------------
    unsigned long long mask_a = __ballot(act);
    int rank = __popcll(mask_a & ((1ull << lane) - 1));
    if (act) tbl[rank] = lane;
    __syncthreads();
    int srcl = tbl[lane & 63];
    int src2 = (lane < 48) ? srcl : lane;
#pragma unroll
    for (int t = 0; t < 64; ++t) a[t] = __shfl(a[t], src2);
    if (lane >= 48) {
        const float* Brow = &Ms[24 + (lane - 48)][0];
#pragma unroll
        for (int q = 0; q < 16; ++q) {
            float4 v4 = *(const float4*)&Brow[4 * q];
            a[4 * q] = v4.x; a[4 * q + 1] = v4.y; a[4 * q + 2] = v4.z; a[4 * q + 3] = v4.w;
        }
    }
    int rowid = (lane < 48) ? srcl : (16 + lane);
    act = true;

    // ---------------- phase 2: k = 16..79 ----------------
#pragma unroll 1
    for (int k = 16; k < 80; ++k) {
        int rem = 79 - k;
        float cand = act ? fabsf(a[0]) : -1.f;
        float m = cand;
        DPPMAX(m, 0x111); DPPMAX(m, 0x112); DPPMAX(m, 0x114); DPPMAX(m, 0x118);
        DPPMAX(m, 0x142); DPPMAX(m, 0x143);
        float mx = rdlane(m, 63);
        unsigned long long sel = __ballot(act && cand == mx);
        int p = __ffsll(sel) - 1;

        int pr = rdlanei(rowid, p);
        inv += __popcll(__ballot(act && rowid < pr));

        float piv = rdlane(a[0], p);
        det *= (double)piv;
        if (lane == p) act = false;
        float la = (act && piv != 0.f) ? a[0] / piv : 0.f;

#pragma unroll
        for (int tb = 0; tb < 4; ++tb) {
            if (16 * tb < rem) {
#pragma unroll
                for (int i = 0; i < 16; ++i) {
                    float u = rdlane(a[16 * tb + i + 1], p);
                    a[16 * tb + i] = fmaf(-la, u, a[16 * tb + i + 1]);
                }
            }
        }
    }

    if (lane == 0) {
        double sgn = (inv & 1) ? -1.0 : 1.0;
        atomicAdd(&out[b], (float)(det * sgn * (double)ci_w[c]));
    }
}

// ---- A: pin waves/EU to 1 -> arch-VGPR budget 512/wave. If round-6's AGPR
//      traffic was pressure-driven spill, this variant keeps a[81] in arch
//      VGPRs (expect VGPR_Count>=130 and ~3-4x faster per block).
template <bool USE_G>
__global__ __launch_bounds__(64)
__attribute__((amdgpu_waves_per_eu(1, 1)))
void det_reg_A(const float* __restrict__ ao, const float* __restrict__ mo_w,
               const float* __restrict__ G, const float* __restrict__ ci_w,
               const int* __restrict__ conf_idx, float* __restrict__ out) {
    det_body<USE_G>(ao, mo_w, G, ci_w, conf_idx, out);
}

// ---- B: control, exact round-6 configuration (VGPR_Count=96, ~100us/2048blk).
template <bool USE_G>
__global__ __launch_bounds__(64)
void det_reg_B(const float* __restrict__ ao, const float* __restrict__ mo_w,
               const float* __restrict__ G, const float* __restrict__ ci_w,
               const int* __restrict__ conf_idx, float* __restrict__ out) {
    det_body<USE_G>(ao, mo_w, G, ci_w, conf_idx, out);
}

extern "C" void kernel_launch(void* const* d_in, const int* in_sizes, int n_in,
                              void* d_out, int out_size, void* d_ws, size_t ws_size,
                              hipStream_t stream) {
    const float* ao    = (const float*)d_in[0];   // (128,192,128) f32
    const float* mo_w  = (const float*)d_in[1];   // (96,128) f32
    const float* ci_w  = (const float*)d_in[2];   // (1,32) f32
    const int*   conf  = (const int*)d_in[3];     // (32,80) i32
    float* out = (float*)d_out;                   // (128,1) f32
    float* G   = (float*)d_ws;

    const size_t g_need = (size_t)B_ * NMO * NMO * sizeof(float);  // 4.72 MB
    const int HC = NCONF / 2;   // 16 configs per variant
    if (ws_size >= g_need) {
        gemm_g_k<<<dim3(B_, 6), dim3(256), 0, stream>>>(ao, mo_w, G, out);
        det_reg_A<true><<<dim3(HC, B_), dim3(64), 0, stream>>>(ao, mo_w, G, ci_w, conf, out);
        det_reg_B<true><<<dim3(HC, B_), dim3(64), 0, stream>>>(ao, mo_w, G, ci_w + HC,
                                                               conf + HC * L_, out);
    } else {
        zero_out_k<<<dim3(1), dim3(B_), 0, stream>>>(out);
        det_reg_A<false><<<dim3(HC, B_), dim3(64), 0, stream>>>(ao, mo_w, nullptr, ci_w, conf, out);
        det_reg_B<false><<<dim3(HC, B_), dim3(64), 0, stream>>>(ao, mo_w, nullptr, ci_w + HC,
                                                                conf + HC * L_, out);
    }
}